// Round 2
// baseline (232.135 us; speedup 1.0000x reference)
//
#include <hip/hip_runtime.h>
#include <hip/hip_bf16.h>
#include <cstdint>

#define N_NODES 50000
#define N_EDGES 800000
#define D_IN 128
#define D_HID 256
#define D_OUT 128

typedef __bf16 bf16;
typedef __bf16 bf16x8 __attribute__((ext_vector_type(8)));
typedef __bf16 bf16x4 __attribute__((ext_vector_type(4)));
typedef float f32x4 __attribute__((ext_vector_type(4)));

// ---------------------------------------------------------------------------
// Kernel 1: agg = (1+eps)*x  (float4), and convert/transpose weights to bf16.
// w1 [128][256] -> w1t [256][128] (n-major, k contiguous)
// w2 [256][128] -> w2t [128][256]
// grid: 6250 x 256 threads = 1.6M = N*D_IN/4 exactly.
// ---------------------------------------------------------------------------
__global__ __launch_bounds__(256) void prep_kernel(
    const float* __restrict__ x, const float* __restrict__ eps,
    const float* __restrict__ w1, const float* __restrict__ w2,
    float* __restrict__ agg, bf16* __restrict__ w1t, bf16* __restrict__ w2t) {
  const int i = blockIdx.x * 256 + threadIdx.x;
  const float scale = 1.0f + eps[0];
  const float4* x4 = (const float4*)x;
  float4* a4 = (float4*)agg;
  float4 v = x4[i];
  v.x *= scale; v.y *= scale; v.z *= scale; v.w *= scale;
  a4[i] = v;
  if (i < D_IN * D_HID) {            // 32768
    int k = i >> 8, n = i & 255;     // w1[k][n]
    w1t[n * D_IN + k] = (bf16)w1[i];
  } else if (i < 2 * D_IN * D_HID) { // next 32768
    int j = i - D_IN * D_HID;
    int k = j >> 7, n = j & 127;     // w2[k][n]
    w2t[n * D_HID + k] = (bf16)w2[j];
  }
}

// ---------------------------------------------------------------------------
// Kernel 2: segmented scatter-add over sorted edge_dst.
// One wave per 64 contiguous edges; lane owns 2 channels (float2).
// Edge metadata loaded 16-at-a-time from wave-uniform addresses
// (readfirstlane hint -> scalar loads), then 16 INDEPENDENT x-row gathers
// issued before the accumulate pass => 16-deep memory-level parallelism
// (round 1 was latency-bound at MLP~2: VALUBusy 21%, 3.1 TB/s).
// Register-accumulate runs of equal dst; flush with fp32 atomics at run ends.
// grid: 3125 x 256 (4 waves/block) => 12500 waves * 64 edges = 800000 exact.
// ---------------------------------------------------------------------------
__global__ __launch_bounds__(256) void edge_agg_kernel(
    const float* __restrict__ x, const int* __restrict__ src,
    const int* __restrict__ dst, const float* __restrict__ val,
    float* __restrict__ agg) {
  const int wave = (blockIdx.x << 2) | (threadIdx.x >> 6);
  const int lane = threadIdx.x & 63;
  const int e0 = __builtin_amdgcn_readfirstlane(wave << 6);
  const float2* x2 = (const float2*)x;

  float2 acc = make_float2(0.f, 0.f);
  int cur = dst[e0];

  #pragma unroll 1
  for (int j = 0; j < 64; j += 16) {
    int s[16], d[16];
    float v[16];
    #pragma unroll
    for (int t = 0; t < 16; ++t) {
      s[t] = src[e0 + j + t];
      d[t] = dst[e0 + j + t];
      v[t] = val[e0 + j + t];
    }
    float2 g[16];
    #pragma unroll
    for (int t = 0; t < 16; ++t)
      g[t] = x2[(long)s[t] * 64 + lane];
    #pragma unroll
    for (int t = 0; t < 16; ++t) {
      if (d[t] != cur) {  // wave-uniform branch: flush previous run
        unsafeAtomicAdd(&agg[(long)cur * D_IN + lane * 2 + 0], acc.x);
        unsafeAtomicAdd(&agg[(long)cur * D_IN + lane * 2 + 1], acc.y);
        acc.x = 0.f; acc.y = 0.f;
        cur = d[t];
      }
      acc.x = fmaf(v[t], g[t].x, acc.x);
      acc.y = fmaf(v[t], g[t].y, acc.y);
    }
  }
  unsafeAtomicAdd(&agg[(long)cur * D_IN + lane * 2 + 0], acc.x);
  unsafeAtomicAdd(&agg[(long)cur * D_IN + lane * 2 + 1], acc.y);
}

// ---------------------------------------------------------------------------
// Kernel 3: fully fused MLP: out = relu(agg @ w1 + b1) @ w2 + b2.
// Block = 256 thr = 4 waves; tile = 64 rows. Each wave owns 16 rows.
// Phase 1: A-frags straight from global (8 consecutive fp32/lane),
//          B-frags straight from global w1t (16 B/lane, L1/L2-resident),
//          h (16x256/wave) -> bias+relu -> bf16 -> LDS (C-layout->A-layout
//          transpose; wave-private rows => NO barrier needed).
// Phase 2: A2-frags via ds_read_b128, B2 from w2t global, fp32 out + bias.
// LDS 64x264 bf16 = 33 KB => ~4 blocks/CU. Stride 264: 16B-aligned reads,
// worst-case 2-way bank aliasing (free per m136).
// Fragment layouts verified in round 1 (absmax 0.0625):
//   A: a[j]=A[lane&15][quad*8+j]; B: b[j]=Wt[lane&15][quad*8+j] (n-major);
//   C: acc[r] -> row=quad*4+r, col=lane&15.
// ---------------------------------------------------------------------------
__global__ __launch_bounds__(256) void fused_mlp(
    const float* __restrict__ A, const bf16* __restrict__ w1t,
    const float* __restrict__ b1, const bf16* __restrict__ w2t,
    const float* __restrict__ b2, float* __restrict__ out) {
  constexpr int LDH = D_HID + 8;  // 264 bf16 = 528 B row stride
  __shared__ alignas(16) bf16 hs[64][LDH];

  const int tid = threadIdx.x;
  const int wave = tid >> 6;
  const int lane = tid & 63;
  const int l15 = lane & 15;
  const int quad = lane >> 4;
  const int m0 = blockIdx.x * 64;
  const int wrow = wave * 16;  // wave's row offset within the 64-row tile

  int arow = m0 + wrow + l15;
  if (arow >= N_NODES) arow = N_NODES - 1;  // clamp loads; stores are guarded

  // ---- load A fragments for all 4 k-steps (8 fp32 -> bf16x8 each) ----
  bf16x8 afrag[4];
  const float4* Arow = (const float4*)&A[(long)arow * D_IN];
  #pragma unroll
  for (int ks = 0; ks < 4; ++ks) {
    float4 lo = Arow[ks * 8 + quad * 2 + 0];
    float4 hi = Arow[ks * 8 + quad * 2 + 1];
    afrag[ks] = bf16x8{(bf16)lo.x, (bf16)lo.y, (bf16)lo.z, (bf16)lo.w,
                       (bf16)hi.x, (bf16)hi.y, (bf16)hi.z, (bf16)hi.w};
  }

  // ---- phase 1: h = relu(A @ w1 + b1), write bf16 to LDS (transpose) ----
  #pragma unroll
  for (int nt = 0; nt < D_HID / 16; ++nt) {  // 16 n-tiles
    f32x4 acc = {};
    const bf16* Bp = &w1t[(nt * 16 + l15) * D_IN];
    #pragma unroll
    for (int ks = 0; ks < 4; ++ks) {
      bf16x8 bfrag = *(const bf16x8*)&Bp[ks * 32 + quad * 8];
      acc = __builtin_amdgcn_mfma_f32_16x16x32_bf16(afrag[ks], bfrag, acc, 0, 0, 0);
    }
    float bv = b1[nt * 16 + l15];
    #pragma unroll
    for (int r = 0; r < 4; ++r) {
      float hv = fmaxf(acc[r] + bv, 0.f);
      hs[wrow + quad * 4 + r][nt * 16 + l15] = (bf16)hv;
    }
  }
  // no __syncthreads: each wave reads only the rows it wrote; compiler
  // inserts the lgkmcnt wait for the LDS write->read dependency.

  // ---- phase 2: out = h @ w2 + b2 ----
  bf16x8 a2[8];
  #pragma unroll
  for (int ks = 0; ks < 8; ++ks)
    a2[ks] = *(const bf16x8*)&hs[wrow + l15][ks * 32 + quad * 8];

  f32x4 acc2[D_OUT / 16] = {};
  #pragma unroll
  for (int nt = 0; nt < D_OUT / 16; ++nt) {  // 8 n-tiles
    const bf16* Bp = &w2t[(nt * 16 + l15) * D_HID];
    #pragma unroll
    for (int ks = 0; ks < 8; ++ks) {
      bf16x8 bfrag = *(const bf16x8*)&Bp[ks * 32 + quad * 8];
      acc2[nt] = __builtin_amdgcn_mfma_f32_16x16x32_bf16(a2[ks], bfrag, acc2[nt], 0, 0, 0);
    }
  }

  #pragma unroll
  for (int nt = 0; nt < D_OUT / 16; ++nt) {
    float bv = b2[nt * 16 + l15];
    #pragma unroll
    for (int r = 0; r < 4; ++r) {
      int row = m0 + wrow + quad * 4 + r;
      if (row < N_NODES)
        out[(long)row * D_OUT + nt * 16 + l15] = acc2[nt][r] + bv;
    }
  }
}

// ---------------------------------------------------------------------------
extern "C" void kernel_launch(void* const* d_in, const int* in_sizes, int n_in,
                              void* d_out, int out_size, void* d_ws, size_t ws_size,
                              hipStream_t stream) {
  const float* x    = (const float*)d_in[0];
  const int*   esrc = (const int*)d_in[1];
  const int*   edst = (const int*)d_in[2];
  const float* evl  = (const float*)d_in[3];
  const float* eps  = (const float*)d_in[4];
  const float* w1   = (const float*)d_in[5];
  const float* b1   = (const float*)d_in[6];
  const float* w2   = (const float*)d_in[7];
  const float* b2   = (const float*)d_in[8];
  float* out = (float*)d_out;

  // workspace layout (16B aligned)
  float* agg = (float*)d_ws;                                      // 25.6 MB
  bf16*  w1t = (bf16*)((char*)d_ws + (size_t)N_NODES * D_IN * 4); // 64 KB
  bf16*  w2t = w1t + D_IN * D_HID;                                // 64 KB

  prep_kernel<<<(N_NODES * D_IN / 4) / 256, 256, 0, stream>>>(
      x, eps, w1, w2, agg, w1t, w2t);
  edge_agg_kernel<<<N_EDGES / 256, 256, 0, stream>>>(x, esrc, edst, evl, agg);
  fused_mlp<<<(N_NODES + 63) / 64, 256, 0, stream>>>(agg, w1t, b1, w2t, b2, out);
}

// Round 3
// 195.056 us; speedup vs baseline: 1.1901x; 1.1901x over previous
//
#include <hip/hip_runtime.h>
#include <hip/hip_bf16.h>
#include <cstdint>

#define N_NODES 50000
#define N_EDGES 800000
#define D_IN 128
#define D_HID 256
#define D_OUT 128

typedef __bf16 bf16;
typedef __bf16 bf16x8 __attribute__((ext_vector_type(8)));
typedef __bf16 bf16x4 __attribute__((ext_vector_type(4)));
typedef __bf16 bf16x2 __attribute__((ext_vector_type(2)));
typedef float f32x4 __attribute__((ext_vector_type(4)));

// ---------------------------------------------------------------------------
// Kernel 1: agg = (1+eps)*x (fp32), xb = bf16(x) for the edge gather,
// and convert/transpose weights to bf16 (n-major, k contiguous).
// grid: 6250 x 256 threads = 1.6M = N*D_IN/4 exactly.
// ---------------------------------------------------------------------------
__global__ __launch_bounds__(256) void prep_kernel(
    const float* __restrict__ x, const float* __restrict__ eps,
    const float* __restrict__ w1, const float* __restrict__ w2,
    float* __restrict__ agg, bf16* __restrict__ xb,
    bf16* __restrict__ w1t, bf16* __restrict__ w2t) {
  const int i = blockIdx.x * 256 + threadIdx.x;
  const float scale = 1.0f + eps[0];
  const float4* x4 = (const float4*)x;
  float4 v = x4[i];
  // raw x in bf16 for the gather
  ((bf16x4*)xb)[i] = bf16x4{(bf16)v.x, (bf16)v.y, (bf16)v.z, (bf16)v.w};
  // scaled self-term
  float4 s = make_float4(v.x * scale, v.y * scale, v.z * scale, v.w * scale);
  ((float4*)agg)[i] = s;
  if (i < D_IN * D_HID) {            // 32768
    int k = i >> 8, n = i & 255;     // w1[k][n]
    w1t[n * D_IN + k] = (bf16)w1[i];
  } else if (i < 2 * D_IN * D_HID) { // next 32768
    int j = i - D_IN * D_HID;
    int k = j >> 7, n = j & 127;     // w2[k][n]
    w2t[n * D_HID + k] = (bf16)w2[j];
  }
}

// ---------------------------------------------------------------------------
// Kernel 2: segmented scatter-add over sorted edge_dst, bf16 gather.
// One wave per 64 contiguous edges; lane owns 2 channels.
// 16-deep batched edge metadata (uniform addrs -> scalar loads) + 16
// independent row gathers in flight. bf16 rows = 256 B/row (round 2 showed
// the kernel is EA/L2-miss-bandwidth bound at 3.4 TB/s; halve the bytes).
// Register-accumulate runs of equal dst; flush fp32 atomics at run ends.
// ---------------------------------------------------------------------------
__global__ __launch_bounds__(256) void edge_agg_kernel(
    const bf16* __restrict__ xb, const int* __restrict__ src,
    const int* __restrict__ dst, const float* __restrict__ val,
    float* __restrict__ agg) {
  const int wave = (blockIdx.x << 2) | (threadIdx.x >> 6);
  const int lane = threadIdx.x & 63;
  const int e0 = __builtin_amdgcn_readfirstlane(wave << 6);

  float2 acc = make_float2(0.f, 0.f);
  int cur = dst[e0];

  #pragma unroll 1
  for (int j = 0; j < 64; j += 16) {
    int s[16], d[16];
    float v[16];
    #pragma unroll
    for (int t = 0; t < 16; ++t) {
      s[t] = src[e0 + j + t];
      d[t] = dst[e0 + j + t];
      v[t] = val[e0 + j + t];
    }
    float2 g[16];
    #pragma unroll
    for (int t = 0; t < 16; ++t) {
      bf16x2 p = *(const bf16x2*)&xb[(long)s[t] * D_IN + lane * 2];
      g[t] = make_float2((float)p.x, (float)p.y);
    }
    #pragma unroll
    for (int t = 0; t < 16; ++t) {
      if (d[t] != cur) {  // wave-uniform branch: flush previous run
        unsafeAtomicAdd(&agg[(long)cur * D_IN + lane * 2 + 0], acc.x);
        unsafeAtomicAdd(&agg[(long)cur * D_IN + lane * 2 + 1], acc.y);
        acc.x = 0.f; acc.y = 0.f;
        cur = d[t];
      }
      acc.x = fmaf(v[t], g[t].x, acc.x);
      acc.y = fmaf(v[t], g[t].y, acc.y);
    }
  }
  unsafeAtomicAdd(&agg[(long)cur * D_IN + lane * 2 + 0], acc.x);
  unsafeAtomicAdd(&agg[(long)cur * D_IN + lane * 2 + 1], acc.y);
}

// ---------------------------------------------------------------------------
// Kernel 3: fused MLP, ILP-restructured (round 2 was latency-bound:
// MfmaUtil 3.3%, VGPR 52 -> compiler never hoisted B loads).
//  - 32-row M-tiles -> grid 1563 (2x the waves of round 2)
//  - N split across the block's 4 waves; h shared via LDS + one barrier
//  - ALL B-fragments of a phase loaded into register arrays BEFORE the
//    MFMA block: 16 independent 1KB wave-loads in flight, one wait.
// Fragment layouts as verified in rounds 1-2:
//   A: a[j]=A[l15][quad*8+j]; B: b[j]=Wt[l15 (n)][quad*8+j (k)];
//   C: acc[r] -> row=quad*4+r, col=l15.
// ---------------------------------------------------------------------------
__global__ __launch_bounds__(256) void fused_mlp(
    const float* __restrict__ A, const bf16* __restrict__ w1t,
    const float* __restrict__ b1, const bf16* __restrict__ w2t,
    const float* __restrict__ b2, float* __restrict__ out) {
  constexpr int LDH = D_HID + 8;  // 264 bf16 = 528 B row stride
  __shared__ alignas(16) bf16 hs[32][LDH];

  const int tid = threadIdx.x;
  const int wave = tid >> 6;
  const int lane = tid & 63;
  const int l15 = lane & 15;
  const int quad = lane >> 4;
  const int m0 = blockIdx.x * 32;

  // ---- A fragments for both 16-row subtiles (fp32 -> bf16) ----
  bf16x8 afrag[2][4];
  #pragma unroll
  for (int ms = 0; ms < 2; ++ms) {
    int row = m0 + ms * 16 + l15;
    if (row >= N_NODES) row = N_NODES - 1;  // clamp loads; stores guarded
    const float4* Ar = (const float4*)&A[(long)row * D_IN];
    #pragma unroll
    for (int ks = 0; ks < 4; ++ks) {
      float4 lo = Ar[ks * 8 + quad * 2 + 0];
      float4 hi = Ar[ks * 8 + quad * 2 + 1];
      afrag[ms][ks] = bf16x8{(bf16)lo.x, (bf16)lo.y, (bf16)lo.z, (bf16)lo.w,
                             (bf16)hi.x, (bf16)hi.y, (bf16)hi.z, (bf16)hi.w};
    }
  }

  // ---- phase 1: this wave's 4 n-tiles (nt = wave*4+j) ----
  bf16x8 bfr[4][4];
  #pragma unroll
  for (int j = 0; j < 4; ++j) {
    const bf16* Bp = &w1t[((wave * 4 + j) * 16 + l15) * D_IN];
    #pragma unroll
    for (int ks = 0; ks < 4; ++ks)
      bfr[j][ks] = *(const bf16x8*)&Bp[ks * 32 + quad * 8];
  }
  #pragma unroll
  for (int j = 0; j < 4; ++j) {
    int nt = wave * 4 + j;
    f32x4 acc[2] = {};
    #pragma unroll
    for (int ks = 0; ks < 4; ++ks) {
      acc[0] = __builtin_amdgcn_mfma_f32_16x16x32_bf16(afrag[0][ks], bfr[j][ks], acc[0], 0, 0, 0);
      acc[1] = __builtin_amdgcn_mfma_f32_16x16x32_bf16(afrag[1][ks], bfr[j][ks], acc[1], 0, 0, 0);
    }
    float bv = b1[nt * 16 + l15];
    #pragma unroll
    for (int ms = 0; ms < 2; ++ms)
      #pragma unroll
      for (int r = 0; r < 4; ++r) {
        float hv = fmaxf(acc[ms][r] + bv, 0.f);
        hs[ms * 16 + quad * 4 + r][nt * 16 + l15] = (bf16)hv;
      }
  }
  __syncthreads();

  // ---- phase 2: this wave's 2 output n-tiles (n2t = wave*2+j) ----
  bf16x8 b2f[2][8];
  #pragma unroll
  for (int j = 0; j < 2; ++j) {
    const bf16* Bp = &w2t[((wave * 2 + j) * 16 + l15) * D_HID];
    #pragma unroll
    for (int ks = 0; ks < 8; ++ks)
      b2f[j][ks] = *(const bf16x8*)&Bp[ks * 32 + quad * 8];
  }
  #pragma unroll
  for (int ms = 0; ms < 2; ++ms) {
    bf16x8 a2[8];
    #pragma unroll
    for (int ks = 0; ks < 8; ++ks)
      a2[ks] = *(const bf16x8*)&hs[ms * 16 + l15][ks * 32 + quad * 8];
    #pragma unroll
    for (int j = 0; j < 2; ++j) {
      f32x4 acc = {};
      #pragma unroll
      for (int ks = 0; ks < 8; ++ks)
        acc = __builtin_amdgcn_mfma_f32_16x16x32_bf16(a2[ks], b2f[j][ks], acc, 0, 0, 0);
      int col = (wave * 2 + j) * 16 + l15;
      float bv = b2[col];
      #pragma unroll
      for (int r = 0; r < 4; ++r) {
        int row = m0 + ms * 16 + quad * 4 + r;
        if (row < N_NODES)
          out[(long)row * D_OUT + col] = acc[r] + bv;
      }
    }
  }
}

// ---------------------------------------------------------------------------
extern "C" void kernel_launch(void* const* d_in, const int* in_sizes, int n_in,
                              void* d_out, int out_size, void* d_ws, size_t ws_size,
                              hipStream_t stream) {
  const float* x    = (const float*)d_in[0];
  const int*   esrc = (const int*)d_in[1];
  const int*   edst = (const int*)d_in[2];
  const float* evl  = (const float*)d_in[3];
  const float* eps  = (const float*)d_in[4];
  const float* w1   = (const float*)d_in[5];
  const float* b1   = (const float*)d_in[6];
  const float* w2   = (const float*)d_in[7];
  const float* b2   = (const float*)d_in[8];
  float* out = (float*)d_out;

  // workspace layout (16B aligned)
  float* agg = (float*)d_ws;                                      // 25.6 MB
  bf16*  xb  = (bf16*)((char*)d_ws + (size_t)N_NODES * D_IN * 4); // 12.8 MB
  bf16*  w1t = xb + (size_t)N_NODES * D_IN;                       // 64 KB
  bf16*  w2t = w1t + D_IN * D_HID;                                // 64 KB

  prep_kernel<<<(N_NODES * D_IN / 4) / 256, 256, 0, stream>>>(
      x, eps, w1, w2, agg, xb, w1t, w2t);
  edge_agg_kernel<<<N_EDGES / 256, 256, 0, stream>>>(xb, esrc, edst, evl, agg);
  fused_mlp<<<(N_NODES + 31) / 32, 256, 0, stream>>>(agg, w1t, b1, w2t, b2, out);
}

// Round 4
// 157.168 us; speedup vs baseline: 1.4770x; 1.2411x over previous
//
#include <hip/hip_runtime.h>
#include <hip/hip_bf16.h>
#include <cstdint>
#include <type_traits>

#define N_NODES 50000
#define N_EDGES 800000
#define D_IN 128
#define D_HID 256
#define D_OUT 128

typedef __bf16 bf16;
typedef __bf16 bf16x8 __attribute__((ext_vector_type(8)));
typedef __bf16 bf16x4 __attribute__((ext_vector_type(4)));
typedef float f32x4 __attribute__((ext_vector_type(4)));

// ---------------------------------------------------------------------------
// Kernel 1: aggb = bf16((1+eps)*x), xb = bf16(x), transposed bf16 weights.
// agg is now bf16 so the edge kernel can use packed bf16 atomics and GEMM1
// staging traffic halves. grid: 6250 x 256 = N*D_IN/4 exactly.
// ---------------------------------------------------------------------------
__global__ __launch_bounds__(256) void prep_kernel(
    const float* __restrict__ x, const float* __restrict__ eps,
    const float* __restrict__ w1, const float* __restrict__ w2,
    bf16* __restrict__ aggb, bf16* __restrict__ xb,
    bf16* __restrict__ w1t, bf16* __restrict__ w2t) {
  const int i = blockIdx.x * 256 + threadIdx.x;
  const float scale = 1.0f + eps[0];
  float4 v = ((const float4*)x)[i];
  ((bf16x4*)xb)[i] = bf16x4{(bf16)v.x, (bf16)v.y, (bf16)v.z, (bf16)v.w};
  ((bf16x4*)aggb)[i] = bf16x4{(bf16)(v.x * scale), (bf16)(v.y * scale),
                              (bf16)(v.z * scale), (bf16)(v.w * scale)};
  if (i < D_IN * D_HID) {            // 32768
    int k = i >> 8, n = i & 255;     // w1[k][n]
    w1t[n * D_IN + k] = (bf16)w1[i];
  } else if (i < 2 * D_IN * D_HID) { // next 32768
    int j = i - D_IN * D_HID;
    int k = j >> 7, n = j & 127;     // w2[k][n]
    w2t[n * D_HID + k] = (bf16)w2[j];
  }
}

// ---------------------------------------------------------------------------
// Kernel 2: segmented scatter-add over sorted edge_dst, bf16 gather + bf16
// PACKED atomic flush (global_atomic_pk_add_bf16): halves atomic op count
// (round-3 theory: TCC atomic serialization) and halves agg RMW traffic.
// fp32 accumulation in registers over each run is preserved.
// One wave per 64 edges; lane owns 2 channels; 16-deep gather batches with
// scalarized (wave-uniform) metadata loads.
// ---------------------------------------------------------------------------
__device__ __forceinline__ void flush_pk(bf16* __restrict__ agg, int node,
                                         int lane, float2 acc) {
  union { struct { bf16 x, y; } h; int i; } u;
  u.h.x = (bf16)acc.x; u.h.y = (bf16)acc.y;
  const bf16* p = &agg[(long)node * D_IN + lane * 2];
  asm volatile("global_atomic_pk_add_bf16 %0, %1, off"
               :: "v"(p), "v"(u.i) : "memory");
}

__global__ __launch_bounds__(256) void edge_agg_kernel(
    const bf16* __restrict__ xb, const int* __restrict__ src,
    const int* __restrict__ dst, const float* __restrict__ val,
    bf16* __restrict__ agg) {
  const int wave = (blockIdx.x << 2) | (threadIdx.x >> 6);
  const int lane = threadIdx.x & 63;
  const int e0 = __builtin_amdgcn_readfirstlane(wave << 6);

  float2 acc = make_float2(0.f, 0.f);
  int cur = dst[e0];

  #pragma unroll 1
  for (int j = 0; j < 64; j += 16) {
    int s[16], d[16];
    float v[16];
    #pragma unroll
    for (int t = 0; t < 16; ++t) {
      s[t] = src[e0 + j + t];
      d[t] = dst[e0 + j + t];
      v[t] = val[e0 + j + t];
    }
    int g[16];  // packed bf16x2
    #pragma unroll
    for (int t = 0; t < 16; ++t)
      g[t] = *(const int*)&xb[(long)s[t] * D_IN + lane * 2];
    #pragma unroll
    for (int t = 0; t < 16; ++t) {
      if (d[t] != cur) {  // wave-uniform branch: flush previous run
        flush_pk(agg, cur, lane, acc);
        acc.x = 0.f; acc.y = 0.f;
        cur = d[t];
      }
      float gx = __uint_as_float((unsigned)g[t] << 16);
      float gy = __uint_as_float((unsigned)g[t] & 0xffff0000u);
      acc.x = fmaf(v[t], gx, acc.x);
      acc.y = fmaf(v[t], gy, acc.y);
    }
  }
  flush_pk(agg, cur, lane, acc);
}

// ---------------------------------------------------------------------------
// Kernels 3/4: C[M,NOUT] = act(A[M,KDIM] @ Wt[NOUT,KDIM]^T + bias).
// Round-1 skeleton (LDS-staged 64x64 tiles) with bf16 A, split into two
// dispatches for rocprof visibility of the ~50 us MLP mystery.
// Fragment layouts verified rounds 1-3:
//   A: a[j]=A[l15][quad*8+j]; B: b[j]=Wt[l15][quad*8+j]; C: row=quad*4+r, col=l15.
// ---------------------------------------------------------------------------
template <int KDIM, int NOUT, bool RELU, typename TC>
__global__ __launch_bounds__(256) void gemm(
    const bf16* __restrict__ A, const bf16* __restrict__ Wt,
    const float* __restrict__ bias, TC* __restrict__ C) {
  constexpr int LDL = 136;  // 272 B row stride: 2-way bank aliasing only
  __shared__ alignas(16) bf16 As[64][LDL];
  __shared__ alignas(16) bf16 Bs[64][LDL];

  const int tid = threadIdx.x;
  const int m0 = blockIdx.x * 64;
  const int n0 = blockIdx.y * 64;
  const int wave = tid >> 6;
  const int lane = tid & 63;
  const int wm = (wave >> 1) * 32;
  const int wn = (wave & 1) * 32;
  const int l15 = lane & 15;
  const int quad = lane >> 4;

  f32x4 acc[2][2] = {};

  for (int kt = 0; kt < KDIM; kt += 128) {
    #pragma unroll
    for (int it = 0; it < 4; ++it) {
      int idx = tid + it * 256;          // 0..1023
      int r = idx >> 4;                  // 16 chunks of 8 bf16 per row
      int c8 = (idx & 15) << 3;
      int row = m0 + r; if (row >= N_NODES) row = N_NODES - 1;
      *(bf16x8*)&As[r][c8] = *(const bf16x8*)&A[(long)row * KDIM + kt + c8];
    }
    #pragma unroll
    for (int it = 0; it < 4; ++it) {
      int idx = tid + it * 256;
      int r = idx >> 4;
      int c8 = (idx & 15) << 3;
      *(bf16x8*)&Bs[r][c8] = *(const bf16x8*)&Wt[(long)(n0 + r) * KDIM + kt + c8];
    }
    __syncthreads();

    #pragma unroll
    for (int ks = 0; ks < 4; ++ks) {
      int kq = ks * 32 + quad * 8;
      bf16x8 a0 = *(const bf16x8*)&As[wm + l15][kq];
      bf16x8 a1 = *(const bf16x8*)&As[wm + 16 + l15][kq];
      bf16x8 b0 = *(const bf16x8*)&Bs[wn + l15][kq];
      bf16x8 b1 = *(const bf16x8*)&Bs[wn + 16 + l15][kq];
      acc[0][0] = __builtin_amdgcn_mfma_f32_16x16x32_bf16(a0, b0, acc[0][0], 0, 0, 0);
      acc[0][1] = __builtin_amdgcn_mfma_f32_16x16x32_bf16(a0, b1, acc[0][1], 0, 0, 0);
      acc[1][0] = __builtin_amdgcn_mfma_f32_16x16x32_bf16(a1, b0, acc[1][0], 0, 0, 0);
      acc[1][1] = __builtin_amdgcn_mfma_f32_16x16x32_bf16(a1, b1, acc[1][1], 0, 0, 0);
    }
    __syncthreads();
  }

  #pragma unroll
  for (int mf = 0; mf < 2; ++mf) {
    #pragma unroll
    for (int nf = 0; nf < 2; ++nf) {
      int col = n0 + wn + nf * 16 + l15;
      float bv = bias[col];
      #pragma unroll
      for (int r = 0; r < 4; ++r) {
        int row = m0 + wm + mf * 16 + quad * 4 + r;
        if (row < N_NODES) {
          float vv = acc[mf][nf][r] + bv;
          if constexpr (RELU) vv = fmaxf(vv, 0.f);
          if constexpr (std::is_same_v<TC, float>)
            C[(long)row * NOUT + col] = vv;
          else
            C[(long)row * NOUT + col] = (bf16)vv;
        }
      }
    }
  }
}

// ---------------------------------------------------------------------------
extern "C" void kernel_launch(void* const* d_in, const int* in_sizes, int n_in,
                              void* d_out, int out_size, void* d_ws, size_t ws_size,
                              hipStream_t stream) {
  const float* x    = (const float*)d_in[0];
  const int*   esrc = (const int*)d_in[1];
  const int*   edst = (const int*)d_in[2];
  const float* evl  = (const float*)d_in[3];
  const float* eps  = (const float*)d_in[4];
  const float* w1   = (const float*)d_in[5];
  const float* b1   = (const float*)d_in[6];
  const float* w2   = (const float*)d_in[7];
  const float* b2   = (const float*)d_in[8];
  float* out = (float*)d_out;

  // workspace layout (16B aligned)
  bf16* aggb = (bf16*)d_ws;                       // 12.8 MB
  bf16* xb   = aggb + (size_t)N_NODES * D_IN;     // 12.8 MB
  bf16* h    = xb + (size_t)N_NODES * D_IN;       // 25.6 MB
  bf16* w1t  = h + (size_t)N_NODES * D_HID;       // 64 KB
  bf16* w2t  = w1t + D_IN * D_HID;                // 64 KB

  prep_kernel<<<(N_NODES * D_IN / 4) / 256, 256, 0, stream>>>(
      x, eps, w1, w2, aggb, xb, w1t, w2t);
  edge_agg_kernel<<<N_EDGES / 256, 256, 0, stream>>>(xb, esrc, edst, evl, aggb);
  gemm<D_IN, D_HID, true, bf16>
      <<<dim3((N_NODES + 63) / 64, D_HID / 64), 256, 0, stream>>>(aggb, w1t, b1, h);
  gemm<D_HID, D_OUT, false, float>
      <<<dim3((N_NODES + 63) / 64, D_OUT / 64), 256, 0, stream>>>(h, w2t, b2, out);
}